// Round 2
// baseline (3675.909 us; speedup 1.0000x reference)
//
#include <hip/hip_runtime.h>
#include <math.h>

// Problem dims
constexpr int Bsz  = 512;
constexpr int Nseq = 64;
constexpr int DX   = 4;
constexpr int MET  = 4;
constexpr int Hd   = 512;
constexpr int H3d  = 1536;

constexpr float RTOL_C = 1e-3f;
constexpr float ATOL_C = 1e-5f;

// ---- Dopri5 tableau (exactly as in jax.experimental.ode, f64->f32) ----
constexpr float SB10 = (float)(1.0/5.0);
constexpr float SB20 = (float)(3.0/40.0),  SB21 = (float)(9.0/40.0);
constexpr float SB30 = (float)(44.0/45.0), SB31 = (float)(-56.0/15.0), SB32 = (float)(32.0/9.0);
constexpr float SB40 = (float)(19372.0/6561.0), SB41 = (float)(-25360.0/2187.0),
                SB42 = (float)(64448.0/6561.0), SB43 = (float)(-212.0/729.0);
constexpr float SB50 = (float)(9017.0/3168.0),  SB51 = (float)(-355.0/33.0),
                SB52 = (float)(46732.0/5247.0), SB53 = (float)(49.0/176.0),
                SB54 = (float)(-5103.0/18656.0);
constexpr float CS0 = (float)(35.0/384.0), CS2 = (float)(500.0/1113.0),
                CS3 = (float)(125.0/192.0), CS4 = (float)(-2187.0/6784.0),
                CS5 = (float)(11.0/84.0);
// Shampine error coefficients (c_sol - c_star), as written in jax ode.py
constexpr float CE0 = (float)(35.0/384.0 - 1951.0/21600.0);
constexpr float CE2 = (float)(500.0/1113.0 - 22642.0/50085.0);
constexpr float CE3 = (float)(125.0/192.0 - 451.0/720.0);
constexpr float CE4 = (float)(-2187.0/6784.0 + 12231.0/42400.0);
constexpr float CE5 = (float)(11.0/84.0 - 649.0/6300.0);
constexpr float CE6 = (float)(-1.0/60.0);
// dps_c_mid for interpolation fit
constexpr float CM0 = (float)(6025192743.0/30085553152.0/2.0);
constexpr float CM2 = (float)(51252292925.0/65400821598.0/2.0);
constexpr float CM3 = (float)(-2691868925.0/45128329728.0/2.0);
constexpr float CM4 = (float)(187940372067.0/1594534317056.0/2.0);
constexpr float CM5 = (float)(-1776094331.0/19743644256.0/2.0);
constexpr float CM6 = (float)(11237099.0/235043384.0/2.0);

__device__ __forceinline__ float selu_f(float v) {
  const float scl = 1.0507009873554805f;
  const float alp = 1.6732632423543772f;
  float e = v > 0.f ? v : alp * expm1f(v);
  return scl * e;
}
__device__ __forceinline__ float sigmoid_f(float v) {
  return 1.f / (1.f + expf(-v));
}

// ---------------- weight repack kernels ----------------
// W: (R,K) row-major -> P[k/4][R][4] so inner k-loop uses one float4/row
__global__ void pack_kT4(const float* __restrict__ W, float* __restrict__ P, int R, int K) {
  int i = blockIdx.x * 256 + threadIdx.x;
  if (i >= R * K) return;
  int r = i / K, k = i % K;
  P[(k >> 2) * (R * 4) + r * 4 + (k & 3)] = W[i];
}
// plain transpose (R,C) -> (C,R)
__global__ void transpose_k(const float* __restrict__ W, float* __restrict__ T, int R, int C) {
  int i = blockIdx.x * 256 + threadIdx.x;
  if (i >= R * C) return;
  int r = i / C, c = i % C;
  T[c * R + r] = W[i];
}

// ---------------- GRU step: h_out = GRUCell(xm_t, h_in) ----------------
// grid (64,8) blocks, 256 thr. Block tile: 8 batch rows x 64 hidden cols.
// (8-row tile -> 512 blocks -> 8 waves/CU for latency hiding; GRU step was
//  latency-bound at 4 waves/CU, 29us vs 5us compute floor.)
__global__ __launch_bounds__(256) void gru_step_kernel(
    const float* __restrict__ x, const float* __restrict__ meta,
    const float* __restrict__ WihT, const float* __restrict__ WhhP,
    const float* __restrict__ bih, const float* __restrict__ bhh,
    const float* __restrict__ h_in, float* __restrict__ h_out, int t)
{
  __shared__ __align__(16) float hs[8 * Hd];
  const int tid  = threadIdx.x;
  const int jl   = tid & 63;
  const int bsub = tid >> 6;                 // 0..3, each owns 2 batch rows
  const int j    = blockIdx.y * 64 + jl;
  const int b0   = blockIdx.x * 8;

  for (int i = tid; i < 8 * Hd; i += 256) hs[i] = h_in[b0 * Hd + i];
  __syncthreads();

  float ar[2], az[2], an[2];
#pragma unroll
  for (int m = 0; m < 2; ++m) { ar[m] = 0.f; az[m] = 0.f; an[m] = 0.f; }

#pragma unroll 4
  for (int k4 = 0; k4 < Hd / 4; ++k4) {
    const float4 wr = *(const float4*)&WhhP[(k4 * H3d + j) * 4];
    const float4 wz = *(const float4*)&WhhP[(k4 * H3d + 512 + j) * 4];
    const float4 wn = *(const float4*)&WhhP[(k4 * H3d + 1024 + j) * 4];
#pragma unroll
    for (int m = 0; m < 2; ++m) {
      const float4 hv = *(const float4*)&hs[(bsub * 2 + m) * Hd + k4 * 4];
      ar[m] += wr.x * hv.x + wr.y * hv.y + wr.z * hv.z + wr.w * hv.w;
      az[m] += wz.x * hv.x + wz.y * hv.y + wz.z * hv.z + wz.w * hv.w;
      an[m] += wn.x * hv.x + wn.y * hv.y + wn.z * hv.z + wn.w * hv.w;
    }
  }

  const float bihr = bih[j], bihz = bih[512 + j], bihn = bih[1024 + j];
  const float bhhr = bhh[j], bhhz = bhh[512 + j], bhhn = bhh[1024 + j];
  float wir[8], wiz[8], win[8];
#pragma unroll
  for (int kk = 0; kk < 8; ++kk) {
    wir[kk] = WihT[kk * H3d + j];
    wiz[kk] = WihT[kk * H3d + 512 + j];
    win[kk] = WihT[kk * H3d + 1024 + j];
  }

#pragma unroll
  for (int m = 0; m < 2; ++m) {
    const int bl = bsub * 2 + m;
    const int b  = b0 + bl;
    const float4 xv = *(const float4*)&x[(b * Nseq + t) * DX];
    const float4 mv = *(const float4*)&meta[b * MET];
    float xm[8] = { xv.x, xv.y, xv.z, xv.w, mv.x, mv.y, mv.z, mv.w };
    float gr = bihr, gz = bihz, gn = bihn;
#pragma unroll
    for (int kk = 0; kk < 8; ++kk) {
      gr += xm[kk] * wir[kk];
      gz += xm[kk] * wiz[kk];
      gn += xm[kk] * win[kk];
    }
    const float ghr = ar[m] + bhhr;
    const float ghz = az[m] + bhhz;
    const float ghn = an[m] + bhhn;
    const float r = sigmoid_f(gr + ghr);
    const float z = sigmoid_f(gz + ghz);
    const float n = tanhf(gn + r * ghn);
    const float hold = hs[bl * Hd + j];
    h_out[b * Hd + j] = (1.f - z) * n + z * hold;
  }
}

// ---------------- encoder layer 1: relu(A @ W^T + b) ----------------
__global__ __launch_bounds__(256) void gemm_relu_kernel(
    const float* __restrict__ A, const float* __restrict__ WP,
    const float* __restrict__ bias, float* __restrict__ Cout)
{
  __shared__ __align__(16) float as[16 * Hd];
  const int tid  = threadIdx.x;
  const int jl   = tid & 63;
  const int bsub = tid >> 6;
  const int j    = blockIdx.y * 64 + jl;
  const int b0   = blockIdx.x * 16;

  for (int i = tid; i < 16 * Hd; i += 256) as[i] = A[b0 * Hd + i];
  __syncthreads();

  float acc[4] = {0.f, 0.f, 0.f, 0.f};
#pragma unroll 2
  for (int k4 = 0; k4 < Hd / 4; ++k4) {
    const float4 w = *(const float4*)&WP[(k4 * Hd + j) * 4];
#pragma unroll
    for (int m = 0; m < 4; ++m) {
      const float4 av = *(const float4*)&as[(bsub * 4 + m) * Hd + k4 * 4];
      acc[m] += w.x * av.x + w.y * av.y + w.z * av.z + w.w * av.w;
    }
  }
  const float bj = bias[j];
#pragma unroll
  for (int m = 0; m < 4; ++m) {
    const int b = b0 + bsub * 4 + m;
    float v = acc[m] + bj;
    Cout[b * Hd + j] = v > 0.f ? v : 0.f;
  }
}

// ---------------- encoder layer 2 + reparam: z0 = eps*std + mean ----------------
__global__ __launch_bounds__(256) void enc2_z0_kernel(
    const float* __restrict__ O1, const float* __restrict__ W2P,  // [k4][1024][4]
    const float* __restrict__ b2, const float* __restrict__ eps,
    float* __restrict__ z0)
{
  __shared__ __align__(16) float as[16 * Hd];
  const int tid  = threadIdx.x;
  const int jl   = tid & 63;
  const int bsub = tid >> 6;
  const int j    = blockIdx.y * 64 + jl;
  const int b0   = blockIdx.x * 16;

  for (int i = tid; i < 16 * Hd; i += 256) as[i] = O1[b0 * Hd + i];
  __syncthreads();

  float am[4] = {0.f, 0.f, 0.f, 0.f};
  float asd[4] = {0.f, 0.f, 0.f, 0.f};
#pragma unroll 2
  for (int k4 = 0; k4 < Hd / 4; ++k4) {
    const float4 wm = *(const float4*)&W2P[(k4 * 1024 + j) * 4];
    const float4 ws = *(const float4*)&W2P[(k4 * 1024 + 512 + j) * 4];
#pragma unroll
    for (int m = 0; m < 4; ++m) {
      const float4 av = *(const float4*)&as[(bsub * 4 + m) * Hd + k4 * 4];
      am[m]  += wm.x * av.x + wm.y * av.y + wm.z * av.z + wm.w * av.w;
      asd[m] += ws.x * av.x + ws.y * av.y + ws.z * av.z + ws.w * av.w;
    }
  }
  const float bm = b2[j], bs = b2[512 + j];
#pragma unroll
  for (int m = 0; m < 4; ++m) {
    const int b = b0 + bsub * 4 + m;
    const float mean = am[m] + bm;
    const float sd   = asd[m] + bs;
    z0[b * Hd + j] = eps[b * Hd + j] * sd + mean;
  }
}

// ---------------- adaptive Dopri5 ODE solve + final FC ----------------
// 64 blocks x 512 threads; each block integrates 8 batch elements in lockstep.
// (8/block halves the per-XCD L2 weight re-stream, the measured bottleneck:
//  16 blk/XCD x 2MB/drift / 4.3 TB/s ~= 7.4us/drift ~= the 1277us observed.)
// Interp state (py/pf/ym) lives in LDS to keep VGPRs under control.
__global__ __launch_bounds__(512, 1) void ode_fc_kernel(
    const float* __restrict__ x, const float* __restrict__ meta,
    const float* __restrict__ z0in,
    const float* __restrict__ W1P, const float* __restrict__ b1v,
    const float* __restrict__ W2P, const float* __restrict__ b2v,
    const float* __restrict__ fcW, const float* __restrict__ fcb,
    float* __restrict__ outp)
{
  constexpr int GE = 8;                     // elements per block
  __shared__ __align__(16) float zsh[Hd * GE];   // z broadcast, [k][e], 16 KB
  __shared__ float pys[GE * Hd];                 // prev y      (interp state)
  __shared__ float pfs[GE * Hd];                 // prev f
  __shared__ float yms[GE * Hd];                 // midpoint fit
  __shared__ float red[8 * GE];
  const int tid = threadIdx.x;
  const int j   = tid;
  const int bg0 = blockIdx.x * GE;

  const float b1r = b1v[j];
  const float b2r = b2v[j];

  // drift(z) = selu(z@W1^T+b1)@W2^T+b2 for GE elements at once
  auto drift = [&](const float (&in)[GE], float (&out)[GE]) {
    __syncthreads();
    *(float4*)&zsh[j * GE + 0] = make_float4(in[0], in[1], in[2], in[3]);
    *(float4*)&zsh[j * GE + 4] = make_float4(in[4], in[5], in[6], in[7]);
    __syncthreads();
    float u[GE];
#pragma unroll
    for (int g = 0; g < GE; ++g) u[g] = b1r;
#pragma unroll 2
    for (int k4 = 0; k4 < Hd / 4; ++k4) {
      const float4 w   = *(const float4*)&W1P[(k4 * Hd + j) * 4];
      const float4 a0  = *(const float4*)&zsh[(k4 * 4 + 0) * GE + 0];
      const float4 a1  = *(const float4*)&zsh[(k4 * 4 + 0) * GE + 4];
      const float4 b0_ = *(const float4*)&zsh[(k4 * 4 + 1) * GE + 0];
      const float4 b1_ = *(const float4*)&zsh[(k4 * 4 + 1) * GE + 4];
      const float4 c0  = *(const float4*)&zsh[(k4 * 4 + 2) * GE + 0];
      const float4 c1  = *(const float4*)&zsh[(k4 * 4 + 2) * GE + 4];
      const float4 d0  = *(const float4*)&zsh[(k4 * 4 + 3) * GE + 0];
      const float4 d1  = *(const float4*)&zsh[(k4 * 4 + 3) * GE + 4];
      u[0] += w.x * a0.x + w.y * b0_.x + w.z * c0.x + w.w * d0.x;
      u[1] += w.x * a0.y + w.y * b0_.y + w.z * c0.y + w.w * d0.y;
      u[2] += w.x * a0.z + w.y * b0_.z + w.z * c0.z + w.w * d0.z;
      u[3] += w.x * a0.w + w.y * b0_.w + w.z * c0.w + w.w * d0.w;
      u[4] += w.x * a1.x + w.y * b1_.x + w.z * c1.x + w.w * d1.x;
      u[5] += w.x * a1.y + w.y * b1_.y + w.z * c1.y + w.w * d1.y;
      u[6] += w.x * a1.z + w.y * b1_.z + w.z * c1.z + w.w * d1.z;
      u[7] += w.x * a1.w + w.y * b1_.w + w.z * c1.w + w.w * d1.w;
    }
#pragma unroll
    for (int g = 0; g < GE; ++g) u[g] = selu_f(u[g]);
    __syncthreads();
    *(float4*)&zsh[j * GE + 0] = make_float4(u[0], u[1], u[2], u[3]);
    *(float4*)&zsh[j * GE + 4] = make_float4(u[4], u[5], u[6], u[7]);
    __syncthreads();
#pragma unroll
    for (int g = 0; g < GE; ++g) u[g] = b2r;
#pragma unroll 2
    for (int k4 = 0; k4 < Hd / 4; ++k4) {
      const float4 w   = *(const float4*)&W2P[(k4 * Hd + j) * 4];
      const float4 a0  = *(const float4*)&zsh[(k4 * 4 + 0) * GE + 0];
      const float4 a1  = *(const float4*)&zsh[(k4 * 4 + 0) * GE + 4];
      const float4 b0_ = *(const float4*)&zsh[(k4 * 4 + 1) * GE + 0];
      const float4 b1_ = *(const float4*)&zsh[(k4 * 4 + 1) * GE + 4];
      const float4 c0  = *(const float4*)&zsh[(k4 * 4 + 2) * GE + 0];
      const float4 c1  = *(const float4*)&zsh[(k4 * 4 + 2) * GE + 4];
      const float4 d0  = *(const float4*)&zsh[(k4 * 4 + 3) * GE + 0];
      const float4 d1  = *(const float4*)&zsh[(k4 * 4 + 3) * GE + 4];
      u[0] += w.x * a0.x + w.y * b0_.x + w.z * c0.x + w.w * d0.x;
      u[1] += w.x * a0.y + w.y * b0_.y + w.z * c0.y + w.w * d0.y;
      u[2] += w.x * a0.z + w.y * b0_.z + w.z * c0.z + w.w * d0.z;
      u[3] += w.x * a0.w + w.y * b0_.w + w.z * c0.w + w.w * d0.w;
      u[4] += w.x * a1.x + w.y * b1_.x + w.z * c1.x + w.w * d1.x;
      u[5] += w.x * a1.y + w.y * b1_.y + w.z * c1.y + w.w * d1.y;
      u[6] += w.x * a1.z + w.y * b1_.z + w.z * c1.z + w.w * d1.z;
      u[7] += w.x * a1.w + w.y * b1_.w + w.z * c1.w + w.w * d1.w;
    }
#pragma unroll
    for (int g = 0; g < GE; ++g) out[g] = u[g];
  };

  // block-wide sum of GE per-thread values (all threads get identical results)
  auto blocksum = [&](float (&v)[GE], float (&s)[GE]) {
#pragma unroll
    for (int off = 32; off > 0; off >>= 1) {
#pragma unroll
      for (int g = 0; g < GE; ++g) v[g] += __shfl_down(v[g], off);
    }
    __syncthreads();
    if ((tid & 63) == 0) {
      const int w = tid >> 6;
#pragma unroll
      for (int g = 0; g < GE; ++g) red[w * GE + g] = v[g];
    }
    __syncthreads();
#pragma unroll
    for (int g = 0; g < GE; ++g) {
      float t = 0.f;
#pragma unroll
      for (int w = 0; w < 8; ++w) t += red[w * GE + g];
      s[g] = t;
    }
  };

  float y[GE], f[GE];
  float tcur[GE], dtv[GE], tfin[GE], ptv[GE], pdt[GE];
  bool act[GE];

#pragma unroll
  for (int g = 0; g < GE; ++g) {
    y[g]    = z0in[(bg0 + g) * Hd + j];
    tcur[g] = x[((bg0 + g) * Nseq + 0) * DX];
    tfin[g] = x[((bg0 + g) * Nseq + (Nseq - 1)) * DX];
  }

  // f0 = drift(y0)
  drift(y, f);

  // ---- initial step size (Hairer / jax variant) ----
  float sc[GE], q0[GE], q1[GE];
#pragma unroll
  for (int g = 0; g < GE; ++g) {
    sc[g] = ATOL_C + RTOL_C * fabsf(y[g]);
    float a = y[g] / sc[g], b = f[g] / sc[g];
    q0[g] = a * a; q1[g] = b * b;
  }
  float d0s[GE], d1s[GE];
  blocksum(q0, d0s);
  blocksum(q1, d1s);
  float h0[GE];
#pragma unroll
  for (int g = 0; g < GE; ++g) {
    float d0 = sqrtf(d0s[g]), d1 = sqrtf(d1s[g]);
    h0[g] = (d0 < 1e-5f || d1 < 1e-5f) ? 1e-6f : 0.01f * d0 / d1;
  }
  float yin[GE], f1h[GE];
#pragma unroll
  for (int g = 0; g < GE; ++g) yin[g] = y[g] + h0[g] * f[g];
  drift(yin, f1h);
  float q2[GE];
#pragma unroll
  for (int g = 0; g < GE; ++g) {
    float dd = (f1h[g] - f[g]) / sc[g];
    q2[g] = dd * dd;
  }
  float d2s[GE];
  blocksum(q2, d2s);
#pragma unroll
  for (int g = 0; g < GE; ++g) {
    float d1 = sqrtf(d1s[g]);
    float d2 = sqrtf(d2s[g]) / h0[g];
    float h1 = (d1 <= 1e-15f && d2 <= 1e-15f)
                 ? fmaxf(1e-6f, h0[g] * 1e-3f)
                 : powf(0.01f / (d1 + d2), 0.2f);   // jax uses d1+d2 here
    dtv[g] = fminf(100.f * h0[g], h1);
    ptv[g] = tcur[g]; pdt[g] = dtv[g];
    pys[g * Hd + j] = y[g];
    pfs[g * Hd + j] = f[g];
    yms[g * Hd + j] = y[g];
    act[g] = (tcur[g] < tfin[g]) && (dtv[g] > 0.f);
  }

  // ---- adaptive stepping loop ----
  float k2[GE], k3[GE], k4v[GE], k5[GE], k6[GE], k7[GE], y1v[GE];
  for (int iter = 0; iter < 4000; ++iter) {
    bool anyact = false;
#pragma unroll
    for (int g = 0; g < GE; ++g) anyact = anyact || act[g];
    if (!anyact) break;

#pragma unroll
    for (int g = 0; g < GE; ++g) yin[g] = y[g] + dtv[g] * (SB10 * f[g]);
    drift(yin, k2);

#pragma unroll
    for (int g = 0; g < GE; ++g)
      yin[g] = y[g] + dtv[g] * (SB20 * f[g] + SB21 * k2[g]);
    drift(yin, k3);

#pragma unroll
    for (int g = 0; g < GE; ++g)
      yin[g] = y[g] + dtv[g] * (SB30 * f[g] + SB31 * k2[g] + SB32 * k3[g]);
    drift(yin, k4v);

#pragma unroll
    for (int g = 0; g < GE; ++g)
      yin[g] = y[g] + dtv[g] * (SB40 * f[g] + SB41 * k2[g] + SB42 * k3[g] + SB43 * k4v[g]);
    drift(yin, k5);

#pragma unroll
    for (int g = 0; g < GE; ++g)
      yin[g] = y[g] + dtv[g] * (SB50 * f[g] + SB51 * k2[g] + SB52 * k3[g] + SB53 * k4v[g] + SB54 * k5[g]);
    drift(yin, k6);

    // y1 (== 7th-stage input, FSAL)
#pragma unroll
    for (int g = 0; g < GE; ++g)
      y1v[g] = y[g] + dtv[g] * (CS0 * f[g] + CS2 * k3[g] + CS3 * k4v[g] + CS4 * k5[g] + CS5 * k6[g]);
    drift(y1v, k7);

    float rs[GE];
#pragma unroll
    for (int g = 0; g < GE; ++g) {
      const float yerr = dtv[g] * (CE0 * f[g] + CE2 * k3[g] + CE3 * k4v[g] + CE4 * k5[g] + CE5 * k6[g] + CE6 * k7[g]);
      const float tol = ATOL_C + RTOL_C * fmaxf(fabsf(y[g]), fabsf(y1v[g]));
      const float r = yerr / tol;
      rs[g] = r * r;
    }
    float rsum[GE];
    blocksum(rs, rsum);

#pragma unroll
    for (int g = 0; g < GE; ++g) {
      if (!act[g]) continue;
      const float er = sqrtf(rsum[g] * (1.0f / Hd));
      const bool accept = (er <= 1.0f);
      if (accept) {
        yms[g * Hd + j] = y[g] + dtv[g] * (CM0 * f[g] + CM2 * k3[g] + CM3 * k4v[g] + CM4 * k5[g] + CM5 * k6[g] + CM6 * k7[g]);
        pys[g * Hd + j] = y[g];
        pfs[g * Hd + j] = f[g];
        ptv[g] = tcur[g]; pdt[g] = dtv[g];
        y[g] = y1v[g]; f[g] = k7[g];
        tcur[g] = tcur[g] + dtv[g];
      }
      float dtn;
      if (er == 0.0f) {
        dtn = dtv[g] * 10.0f;
      } else {
        const float dfac = (er < 1.0f) ? 1.0f : 0.2f;
        const float fac = fminf(10.0f, fmaxf(0.9f * powf(er, -0.2f), dfac));
        dtn = dtv[g] * fac;
      }
      dtv[g] = fmaxf(dtn, 0.0f);
      act[g] = (tcur[g] < tfin[g]) && (dtv[g] > 0.0f);
    }
  }

  // ---- interpolate at t_final (4th-order fit) and fused FC ----
  const float fcw = fcW[j];
  float s[GE];
#pragma unroll
  for (int g = 0; g < GE; ++g) {
    const float pyv = pys[g * Hd + j];
    const float pfv = pfs[g * Hd + j];
    const float ymv = yms[g * Hd + j];
    const float denom = tcur[g] - ptv[g];
    const float xr = (tfin[g] - ptv[g]) / denom;
    const float dy0 = pdt[g] * pfv;
    const float dy1 = pdt[g] * f[g];
    const float aa = -2.f * dy0 + 2.f * dy1 - 8.f * pyv - 8.f * y[g] + 16.f * ymv;
    const float bb =  5.f * dy0 - 3.f * dy1 + 18.f * pyv + 14.f * y[g] - 32.f * ymv;
    const float cc = -4.f * dy0 + 1.f * dy1 - 11.f * pyv - 5.f * y[g] + 16.f * ymv;
    const float dd = dy0;
    const float ee = pyv;
    const float yf = (((aa * xr + bb) * xr + cc) * xr + dd) * xr + ee;
    s[g] = yf * fcw;
  }
  float ssum[GE];
  blocksum(s, ssum);
  if (tid == 0) {
#pragma unroll
    for (int g = 0; g < GE; ++g) {
      float o = ssum[g] + fcb[0];
#pragma unroll
      for (int m = 0; m < MET; ++m) o += meta[(bg0 + g) * MET + m] * fcW[Hd + m];
      outp[bg0 + g] = o;
    }
  }
}

// ---------------- host launcher ----------------
extern "C" void kernel_launch(void* const* d_in, const int* in_sizes, int n_in,
                              void* d_out, int out_size, void* d_ws, size_t ws_size,
                              hipStream_t stream)
{
  (void)in_sizes; (void)n_in; (void)out_size; (void)ws_size;

  const float* x    = (const float*)d_in[0];
  const float* meta = (const float*)d_in[1];
  const float* eps  = (const float*)d_in[2];
  const float* gWih = (const float*)d_in[3];
  const float* gWhh = (const float*)d_in[4];
  const float* gbih = (const float*)d_in[5];
  const float* gbhh = (const float*)d_in[6];
  const float* eW1  = (const float*)d_in[7];
  const float* eb1  = (const float*)d_in[8];
  const float* eW2  = (const float*)d_in[9];
  const float* eb2  = (const float*)d_in[10];
  const float* oW1  = (const float*)d_in[11];
  const float* ob1  = (const float*)d_in[12];
  const float* oW2  = (const float*)d_in[13];
  const float* ob2  = (const float*)d_in[14];
  const float* fcW  = (const float*)d_in[15];
  const float* fcb  = (const float*)d_in[16];
  float* out = (float*)d_out;
  float* ws  = (float*)d_ws;

  // ws layout (floats)
  float* WhhP = ws + 0;          //  786432
  float* WihT = ws + 786432;     //   12288
  float* eW1P = ws + 798720;     //  262144
  float* eW2P = ws + 1060864;    //  524288
  float* oW1P = ws + 1585152;    //  262144
  float* oW2P = ws + 1847296;    //  262144
  float* hA   = ws + 2109440;    //  262144 (h ping / z0)
  float* hB   = ws + 2371584;    //  262144 (h pong / o1)

  pack_kT4<<<(H3d * Hd + 255) / 256, 256, 0, stream>>>(gWhh, WhhP, H3d, Hd);
  transpose_k<<<(H3d * 8 + 255) / 256, 256, 0, stream>>>(gWih, WihT, H3d, 8);
  pack_kT4<<<(Hd * Hd + 255) / 256, 256, 0, stream>>>(eW1, eW1P, Hd, Hd);
  pack_kT4<<<(1024 * Hd + 255) / 256, 256, 0, stream>>>(eW2, eW2P, 1024, Hd);
  pack_kT4<<<(Hd * Hd + 255) / 256, 256, 0, stream>>>(oW1, oW1P, Hd, Hd);
  pack_kT4<<<(Hd * Hd + 255) / 256, 256, 0, stream>>>(oW2, oW2P, Hd, Hd);
  hipMemsetAsync(hA, 0, (size_t)Bsz * Hd * sizeof(float), stream);

  dim3 ggrid(64, 8);   // 512 blocks: 8 batch rows x 64 cols each
  for (int t = 0; t < Nseq; ++t) {
    const float* hin = (t & 1) ? hB : hA;
    float* hout      = (t & 1) ? hA : hB;
    gru_step_kernel<<<ggrid, 256, 0, stream>>>(x, meta, WihT, WhhP, gbih, gbhh, hin, hout, t);
  }
  // final h in hA
  dim3 egrid(32, 8);
  gemm_relu_kernel<<<egrid, 256, 0, stream>>>(hA, eW1P, eb1, hB);           // o1 -> hB
  enc2_z0_kernel<<<egrid, 256, 0, stream>>>(hB, eW2P, eb2, eps, hA);        // z0 -> hA
  ode_fc_kernel<<<Bsz / 8, 512, 0, stream>>>(x, meta, hA, oW1P, ob1, oW2P, ob2, fcW, fcb, out);
}